// Round 3
// baseline (548.267 us; speedup 1.0000x reference)
//
#include <hip/hip_runtime.h>
#include <math.h>

namespace {
constexpr int kB = 16;
constexpr int kL = 240000;
constexpr int kD = 9;
constexpr float kInvSamp = 1.0f / 24000.0f;
constexpr int kChunk = 2048;
constexpr int kT = 8;              // samples per thread
constexpr int kThreads = 256;      // kChunk / kT
constexpr int kNChunks = (kL + kChunk - 1) / kChunk;  // 118 (last: 384 samp)
constexpr int kNBlocks = kB * kNChunks;               // 1888
constexpr float kSineAmp = 0.1f;
constexpr float kNoiseStd = 0.003f;
constexpr float kNoiseUnv = (float)(0.1 / 3.0);
}  // namespace

// Workspace layout. counter+flag (first 7560 bytes) are zeroed per launch;
// agg/pref are rewritten before their flag is raised each epoch.
struct Ws {
  unsigned long long counter;      // 8 B
  unsigned int flag[kNBlocks];     // 0 = none, 1 = agg ready, 2 = pref ready
  unsigned int pad_;
  unsigned long long agg[kNBlocks];
  unsigned long long pref[kNBlocks];
};

__device__ __forceinline__ double atom_read_d(unsigned long long* p) {
  return __longlong_as_double((long long)atomicAdd(p, 0ull));
}

__global__ __launch_bounds__(kThreads) void sine_fused(
    const float* __restrict__ f0, const float* __restrict__ rand_ini,
    const float* __restrict__ noise, const float* __restrict__ w,
    Ws* __restrict__ ws, float* __restrict__ out) {
  __shared__ double sc[kThreads];
  __shared__ double s_run;
  __shared__ int s_ticket;
  const int tid = threadIdx.x;

  if (tid == 0) s_ticket = (int)atomicAdd(&ws->counter, 1ull);
  __syncthreads();
  const int t = s_ticket;
  const int b = t & 15;   // batch
  const int c = t >> 4;   // chunk within batch; predecessor = ticket t-16
  const int l0 = c * kChunk + tid * kT;
  const bool active = l0 < kL;

  // ---- f0 -> rq, local sum
  float rq[kT];
  float tsum = 0.0f;
  if (active) {
    const float4* f4 = reinterpret_cast<const float4*>(f0 + (size_t)b * kL + l0);
    const float4 a = f4[0], bb = f4[1];
    rq[0] = a.x * kInvSamp; rq[1] = a.y * kInvSamp;
    rq[2] = a.z * kInvSamp; rq[3] = a.w * kInvSamp;
    rq[4] = bb.x * kInvSamp; rq[5] = bb.y * kInvSamp;
    rq[6] = bb.z * kInvSamp; rq[7] = bb.w * kInvSamp;
#pragma unroll
    for (int j = 0; j < kT; ++j) tsum += rq[j];
  } else {
#pragma unroll
    for (int j = 0; j < kT; ++j) rq[j] = 0.0f;
  }

  // ---- issue all noise loads early; latency hides under scan + lookback
  float nz[kT * kD];
  if (active) {
    const float4* n4 =
        reinterpret_cast<const float4*>(noise + ((size_t)b * kL + l0) * kD);
#pragma unroll
    for (int i = 0; i < 18; ++i) {
      const float4 v = n4[i];
      nz[4 * i + 0] = v.x; nz[4 * i + 1] = v.y;
      nz[4 * i + 2] = v.z; nz[4 * i + 3] = v.w;
    }
  }

  // ---- block-wide inclusive scan (double) of per-thread sums
  sc[tid] = (double)tsum;
  __syncthreads();
  for (int ofs = 1; ofs < kThreads; ofs <<= 1) {
    const double u = (tid >= ofs) ? sc[tid - ofs] : 0.0;
    __syncthreads();
    sc[tid] += u;
    __syncthreads();
  }
  const double total = sc[kThreads - 1];

  // ---- publish aggregate, decoupled lookback, publish inclusive prefix
  if (tid == 0) {
    atomicExch(&ws->agg[t], (unsigned long long)__double_as_longlong(total));
    __threadfence();
    atomicExch(&ws->flag[t], 1u);

    double run = 0.0;
    if (c > 0) {
      int i = t - 16;
      while (true) {
        const unsigned int f = atomicOr(&ws->flag[i], 0u);
        if (f == 2u) {
          __threadfence();
          run += atom_read_d(&ws->pref[i]);
          break;
        }
        if (f == 1u) {
          __threadfence();
          run += atom_read_d(&ws->agg[i]);
          if (i < 16) break;  // consumed chunk 0's aggregate
          i -= 16;
        } else {
          __builtin_amdgcn_s_sleep(2);
        }
      }
    }
    atomicExch(&ws->pref[t],
               (unsigned long long)__double_as_longlong(run + total));
    __threadfence();
    atomicExch(&ws->flag[t], 2u);
    s_run = run;
  }
  __syncthreads();

  if (!active) return;

  // exclusive phase base (in cycles) for this thread's first sample
  const double cbase = s_run + sc[tid] - (double)tsum;

  float basef[kD], wv[kD];
#pragma unroll
  for (int d = 0; d < kD; ++d) {
    const double ph = (double)(d + 1) * cbase + (double)rand_ini[b * kD + d];
    basef[d] = (float)(ph - floor(ph));
    wv[d] = w[d];
  }

  float ob[kT];
  float pref = 0.0f;
#pragma unroll
  for (int j = 0; j < kT; ++j) {
    pref += rq[j];  // inclusive local prefix
    const float f = rq[j];
    const float au = (f > 0.0f) ? kSineAmp : 0.0f;
    const float namp = (f > 0.0f) ? kNoiseStd : kNoiseUnv;
    float dots = 0.0f, dotn = 0.0f;
#pragma unroll
    for (int d = 0; d < kD; ++d) {
      const float pf = __builtin_amdgcn_fractf(basef[d] + (float)(d + 1) * pref);
      const float sv = __builtin_amdgcn_sinf(pf);  // sin(2*pi*frac)
      dots = fmaf(wv[d], sv, dots);
      dotn = fmaf(wv[d], nz[j * kD + d], dotn);
    }
    const float x = au * dots + namp * dotn;
    const float e = __expf(2.0f * x);
    ob[j] = 1.0f - 2.0f * __builtin_amdgcn_rcpf(e + 1.0f);  // tanh(x)
  }

  float4* o4 = reinterpret_cast<float4*>(out + (size_t)b * kL + l0);
  o4[0] = make_float4(ob[0], ob[1], ob[2], ob[3]);
  o4[1] = make_float4(ob[4], ob[5], ob[6], ob[7]);
}

extern "C" void kernel_launch(void* const* d_in, const int* in_sizes, int n_in,
                              void* d_out, int out_size, void* d_ws,
                              size_t ws_size, hipStream_t stream) {
  const float* f0 = (const float*)d_in[0];
  const float* rand_ini = (const float*)d_in[1];
  const float* noise = (const float*)d_in[2];
  const float* w = (const float*)d_in[3];
  float* out = (float*)d_out;
  Ws* ws = (Ws*)d_ws;  // needs ~38 KB; ws_size >> that

  // zero ticket counter + flags (contiguous head of Ws) every call so the
  // kernel is deterministic across graph replays
  hipMemsetAsync(d_ws, 0, sizeof(unsigned long long) + sizeof(unsigned int) * kNBlocks,
                 stream);
  sine_fused<<<dim3(kNBlocks), dim3(kThreads), 0, stream>>>(f0, rand_ini, noise,
                                                            w, ws, out);
}

// Round 5
// 164.780 us; speedup vs baseline: 3.3273x; 3.3273x over previous
//
#include <hip/hip_runtime.h>
#include <math.h>

namespace {
constexpr int kB = 16;
constexpr int kL = 240000;
constexpr int kD = 9;
constexpr float kInvSamp = 1.0f / 24000.0f;
constexpr int kChunk = 2048;
constexpr int kT = 8;              // samples per thread
constexpr int kThreads = 256;      // kChunk / kT
constexpr int kNChunks = 118;      // ceil(240000/2048); last chunk 384 samp
constexpr int kNTickets = kB * kNChunks;  // 1888
constexpr float kSineAmp = 0.1f;
constexpr float kNoiseStd = 0.003f;
constexpr float kNoiseUnv = (float)(0.1 / 3.0);
}  // namespace

// ticket t -> batch b = t & 15, chunk c = t >> 4; predecessor ticket = t - 16.
// Ticket issue order == block start order => predecessors are running or done
// (forward progress without co-residency assumptions).
struct Ws {
  unsigned long long counter;    // zeroed per launch
  unsigned int flag[kNTickets];  // zeroed per launch: 0 none, 1 agg, 2 pref
  double agg[kNTickets];         // written before flag=1 each launch
  double pref[kNTickets];        // written before flag=2 each launch
};

__global__ __launch_bounds__(kThreads) void sine_lookback(
    const float* __restrict__ f0, const float* __restrict__ rand_ini,
    const float* __restrict__ noise, const float* __restrict__ w,
    Ws* __restrict__ ws, float* __restrict__ out) {
  __shared__ double sc[kThreads];
  __shared__ double s_run;
  __shared__ int s_ticket;
  const int tid = threadIdx.x;

  if (tid == 0) s_ticket = (int)atomicAdd(&ws->counter, 1ull);
  __syncthreads();
  const int t = s_ticket;
  const int b = t & 15, c = t >> 4;
  const int l0 = c * kChunk + tid * kT;
  const bool active = l0 < kL;

  // ---- f0 -> rq (read once; kept in registers through emit)
  float rq[kT];
  float tsum = 0.0f;
  if (active) {
    const float4* f4 = reinterpret_cast<const float4*>(f0 + (size_t)b * kL + l0);
    const float4 a = f4[0], bb = f4[1];
    rq[0] = a.x * kInvSamp; rq[1] = a.y * kInvSamp;
    rq[2] = a.z * kInvSamp; rq[3] = a.w * kInvSamp;
    rq[4] = bb.x * kInvSamp; rq[5] = bb.y * kInvSamp;
    rq[6] = bb.z * kInvSamp; rq[7] = bb.w * kInvSamp;
#pragma unroll
    for (int j = 0; j < kT; ++j) tsum += rq[j];
  } else {
#pragma unroll
    for (int j = 0; j < kT; ++j) rq[j] = 0.0f;
  }

  // ---- block-wide inclusive scan (double)
  sc[tid] = (double)tsum;
  __syncthreads();
  for (int ofs = 1; ofs < kThreads; ofs <<= 1) {
    const double u = (tid >= ofs) ? sc[tid - ofs] : 0.0;
    __syncthreads();
    sc[tid] += u;
    __syncthreads();
  }
  const double total = sc[kThreads - 1];

  // ---- publish aggregate (value relaxed, flag release)
  if (tid == 0) {
    __hip_atomic_store(&ws->agg[t], total, __ATOMIC_RELAXED,
                       __HIP_MEMORY_SCOPE_AGENT);
    __hip_atomic_store(&ws->flag[t], 1u, __ATOMIC_RELEASE,
                       __HIP_MEMORY_SCOPE_AGENT);
  }

  // ---- wave-parallel decoupled lookback (wave 0 only; LOAD-only polling)
  if (tid < 64) {
    double run = 0.0;  // meaningful on lane 0 only
    int base = c;      // predecessors remaining: chunks [0, base)
    while (base > 0) {
      const int p = base - 1 - tid;  // this lane's chunk (nearest-first)
      unsigned int st = 0;
      double v = 0.0;
      if (p >= 0) {
        const int tk = (p << 4) | b;
        st = __hip_atomic_load(&ws->flag[tk], __ATOMIC_ACQUIRE,
                               __HIP_MEMORY_SCOPE_AGENT);
        if (st == 2u)
          v = __hip_atomic_load(&ws->pref[tk], __ATOMIC_RELAXED,
                                __HIP_MEMORY_SCOPE_AGENT);
        else if (st == 1u)
          v = __hip_atomic_load(&ws->agg[tk], __ATOMIC_RELAXED,
                                __HIP_MEMORY_SCOPE_AGENT);
      }
      const unsigned long long m2 = __ballot(p >= 0 && st == 2u);
      const unsigned long long m0 = __ballot(p >= 0 && st == 0u);
      if (m2 != 0ull) {
        const int k = __ffsll((long long)m2) - 1;  // nearest prefix-ready
        if ((m0 & ((1ull << k) - 1ull)) == 0ull) {
          // lanes < k hold aggs, lane k holds inclusive prefix -> resolved
          double contrib = (tid <= k) ? v : 0.0;
#pragma unroll
          for (int off = 32; off > 0; off >>= 1)
            contrib += __shfl_down(contrib, off, 64);
          if (tid == 0) run += contrib;
          base = 0;
          continue;
        }
        __builtin_amdgcn_s_sleep(1);
      } else if (m0 == 0ull) {
        // whole window agg-ready: consume and move toward chunk 0
        const int cnt = base < 64 ? base : 64;
        double contrib = (tid < cnt) ? v : 0.0;
#pragma unroll
        for (int off = 32; off > 0; off >>= 1)
          contrib += __shfl_down(contrib, off, 64);
        if (tid == 0) run += contrib;
        base -= cnt;
      } else {
        __builtin_amdgcn_s_sleep(1);
      }
    }
    if (tid == 0) {
      __hip_atomic_store(&ws->pref[t], run + total, __ATOMIC_RELAXED,
                         __HIP_MEMORY_SCOPE_AGENT);
      __hip_atomic_store(&ws->flag[t], 2u, __ATOMIC_RELEASE,
                         __HIP_MEMORY_SCOPE_AGENT);
      s_run = run;
    }
  }
  __syncthreads();

  if (!active) return;

  // exclusive phase base (cycles) for this thread's first sample
  const double cbase = s_run + sc[tid] - (double)tsum;

  float basef[kD], wv[kD];
#pragma unroll
  for (int d = 0; d < kD; ++d) {
    const double ph = (double)(d + 1) * cbase + (double)rand_ini[b * kD + d];
    basef[d] = (float)(ph - floor(ph));
    wv[d] = w[d];
  }

  float nz[kT * kD];
  {
    const float4* n4 =
        reinterpret_cast<const float4*>(noise + ((size_t)b * kL + l0) * kD);
#pragma unroll
    for (int i = 0; i < 18; ++i) {
      const float4 x = n4[i];
      nz[4 * i + 0] = x.x; nz[4 * i + 1] = x.y;
      nz[4 * i + 2] = x.z; nz[4 * i + 3] = x.w;
    }
  }

  float ob[kT];
  float pref = 0.0f;
#pragma unroll
  for (int j = 0; j < kT; ++j) {
    pref += rq[j];  // inclusive local prefix
    const float f = rq[j];
    const float au = (f > 0.0f) ? kSineAmp : 0.0f;
    const float namp = (f > 0.0f) ? kNoiseStd : kNoiseUnv;
    float dots = 0.0f, dotn = 0.0f;
#pragma unroll
    for (int d = 0; d < kD; ++d) {
      const float pf = __builtin_amdgcn_fractf(basef[d] + (float)(d + 1) * pref);
      const float sv = __builtin_amdgcn_sinf(pf);  // sin(2*pi*frac)
      dots = fmaf(wv[d], sv, dots);
      dotn = fmaf(wv[d], nz[j * kD + d], dotn);
    }
    const float x = au * dots + namp * dotn;
    const float e = __expf(2.0f * x);
    ob[j] = 1.0f - 2.0f * __builtin_amdgcn_rcpf(e + 1.0f);  // tanh(x)
  }

  float4* o4 = reinterpret_cast<float4*>(out + (size_t)b * kL + l0);
  o4[0] = make_float4(ob[0], ob[1], ob[2], ob[3]);
  o4[1] = make_float4(ob[4], ob[5], ob[6], ob[7]);
}

extern "C" void kernel_launch(void* const* d_in, const int* in_sizes, int n_in,
                              void* d_out, int out_size, void* d_ws,
                              size_t ws_size, hipStream_t stream) {
  const float* f0 = (const float*)d_in[0];
  const float* rand_ini = (const float*)d_in[1];
  const float* noise = (const float*)d_in[2];
  const float* w = (const float*)d_in[3];
  float* out = (float*)d_out;
  Ws* ws = (Ws*)d_ws;  // ~38 KB used

  // zero ticket counter + flags each call (deterministic across replays);
  // agg/pref are rewritten before their flag is raised every epoch
  const size_t head =
      sizeof(unsigned long long) + sizeof(unsigned int) * kNTickets;
  hipMemsetAsync(d_ws, 0, head, stream);
  sine_lookback<<<dim3(kNTickets), dim3(kThreads), 0, stream>>>(
      f0, rand_ini, noise, w, ws, out);
}

// Round 6
// 35.847 us; speedup vs baseline: 15.2946x; 4.5967x over previous
//
#include <hip/hip_runtime.h>
#include <math.h>

namespace {
constexpr int kB = 16;
constexpr int kL = 240000;
constexpr int kD = 9;
constexpr float kInvSamp = 1.0f / 24000.0f;
constexpr int kChunk = 2048;
constexpr int kT = 8;              // samples per thread
constexpr int kThreads = 256;      // kChunk / kT
constexpr int kNChunks = 118;      // ceil(240000/2048); last chunk 384 samp
constexpr float kSineAmp = 0.1f;
constexpr float kNoiseStd = 0.003f;
constexpr float kNoiseUnv = (float)(0.1 / 3.0);
}  // namespace

// ---------------- Pass A: per-chunk sum of rq = f0/SR -> agg[b*118+c]
__global__ __launch_bounds__(kThreads) void sine_pass_a(
    const float* __restrict__ f0, double* __restrict__ agg) {
  const int c = blockIdx.x, b = blockIdx.y, tid = threadIdx.x;
  const int l0 = c * kChunk + tid * kT;
  float s = 0.0f;
  if (l0 < kL) {
    const float4* f4 = reinterpret_cast<const float4*>(f0 + (size_t)b * kL + l0);
    const float4 a = f4[0], bb = f4[1];
    s = ((a.x + a.y) + (a.z + a.w)) + ((bb.x + bb.y) + (bb.z + bb.w));
  }
  __shared__ double red[kThreads];
  red[tid] = (double)s * (double)kInvSamp;
  __syncthreads();
  for (int ofs = kThreads / 2; ofs > 0; ofs >>= 1) {
    if (tid < ofs) red[tid] += red[tid + ofs];
    __syncthreads();
  }
  if (tid == 0) agg[(size_t)b * kNChunks + c] = red[0];
}

// ---------------- Pass C: predecessor reduce + block scan + emit
__global__ __launch_bounds__(kThreads) void sine_emit(
    const float* __restrict__ f0, const float* __restrict__ rand_ini,
    const float* __restrict__ noise, const float* __restrict__ w,
    const double* __restrict__ agg, float* __restrict__ out) {
  __shared__ double sc[kThreads];
  __shared__ double red[kThreads];
  const int c = blockIdx.x, b = blockIdx.y, tid = threadIdx.x;
  const int l0 = c * kChunk + tid * kT;
  const bool active = l0 < kL;

  // ---- f0 -> rq (kept in registers through emit)
  float rq[kT];
  float tsum = 0.0f;
  if (active) {
    const float4* f4 = reinterpret_cast<const float4*>(f0 + (size_t)b * kL + l0);
    const float4 a = f4[0], bb = f4[1];
    rq[0] = a.x * kInvSamp; rq[1] = a.y * kInvSamp;
    rq[2] = a.z * kInvSamp; rq[3] = a.w * kInvSamp;
    rq[4] = bb.x * kInvSamp; rq[5] = bb.y * kInvSamp;
    rq[6] = bb.z * kInvSamp; rq[7] = bb.w * kInvSamp;
#pragma unroll
    for (int j = 0; j < kT; ++j) tsum += rq[j];
  } else {
#pragma unroll
    for (int j = 0; j < kT; ++j) rq[j] = 0.0f;
  }

  // ---- issue noise loads early; latency hides under reduce + scan
  float nz[kT * kD];
  if (active) {
    const float4* n4 =
        reinterpret_cast<const float4*>(noise + ((size_t)b * kL + l0) * kD);
#pragma unroll
    for (int i = 0; i < 18; ++i) {
      const float4 x = n4[i];
      nz[4 * i + 0] = x.x; nz[4 * i + 1] = x.y;
      nz[4 * i + 2] = x.z; nz[4 * i + 3] = x.w;
    }
  }

  // ---- predecessor-aggregate reduce (agg is L2-resident, plain loads;
  //      pass A fully rewrites agg before this kernel runs -> replay-safe)
  red[tid] = (tid < c) ? agg[(size_t)b * kNChunks + tid] : 0.0;
  __syncthreads();
  for (int ofs = kThreads / 2; ofs > 0; ofs >>= 1) {
    if (tid < ofs) red[tid] += red[tid + ofs];
    __syncthreads();
  }
  const double base = red[0];

  // ---- block-wide inclusive scan (double) of per-thread sums
  sc[tid] = (double)tsum;
  __syncthreads();
  for (int ofs = 1; ofs < kThreads; ofs <<= 1) {
    const double u = (tid >= ofs) ? sc[tid - ofs] : 0.0;
    __syncthreads();
    sc[tid] += u;
    __syncthreads();
  }

  if (!active) return;

  // exclusive phase base (cycles) for this thread's first sample
  const double cbase = base + sc[tid] - (double)tsum;

  float basef[kD], wv[kD];
#pragma unroll
  for (int d = 0; d < kD; ++d) {
    const double ph = (double)(d + 1) * cbase + (double)rand_ini[b * kD + d];
    basef[d] = (float)(ph - floor(ph));
    wv[d] = w[d];
  }

  float ob[kT];
  float pref = 0.0f;
#pragma unroll
  for (int j = 0; j < kT; ++j) {
    pref += rq[j];  // inclusive local prefix
    const float f = rq[j];
    const float au = (f > 0.0f) ? kSineAmp : 0.0f;
    const float namp = (f > 0.0f) ? kNoiseStd : kNoiseUnv;
    float dots = 0.0f, dotn = 0.0f;
#pragma unroll
    for (int d = 0; d < kD; ++d) {
      const float pf = __builtin_amdgcn_fractf(basef[d] + (float)(d + 1) * pref);
      const float sv = __builtin_amdgcn_sinf(pf);  // sin(2*pi*frac)
      dots = fmaf(wv[d], sv, dots);
      dotn = fmaf(wv[d], nz[j * kD + d], dotn);
    }
    const float x = au * dots + namp * dotn;
    const float e = __expf(2.0f * x);
    ob[j] = 1.0f - 2.0f * __builtin_amdgcn_rcpf(e + 1.0f);  // tanh(x)
  }

  float4* o4 = reinterpret_cast<float4*>(out + (size_t)b * kL + l0);
  o4[0] = make_float4(ob[0], ob[1], ob[2], ob[3]);
  o4[1] = make_float4(ob[4], ob[5], ob[6], ob[7]);
}

extern "C" void kernel_launch(void* const* d_in, const int* in_sizes, int n_in,
                              void* d_out, int out_size, void* d_ws,
                              size_t ws_size, hipStream_t stream) {
  const float* f0 = (const float*)d_in[0];
  const float* rand_ini = (const float*)d_in[1];
  const float* noise = (const float*)d_in[2];
  const float* w = (const float*)d_in[3];
  float* out = (float*)d_out;
  double* agg = (double*)d_ws;  // kB * kNChunks doubles = 15104 B

  const dim3 grid(kNChunks, kB), block(kThreads);
  sine_pass_a<<<grid, block, 0, stream>>>(f0, agg);
  sine_emit<<<grid, block, 0, stream>>>(f0, rand_ini, noise, w, agg, out);
}